// Round 2
// baseline (733.178 us; speedup 1.0000x reference)
//
#include <hip/hip_runtime.h>

// WindowAttention fused kernel v2 for MI355X (gfx950).
// B=4096 windows, N=49, C=256, H=8, hd=32. fp32 in/out, f16 MFMA inside.
//
// One block = one window (512 thr = 8 waves), wave w owns head w end-to-end.
// LDS: xs (25.9 KB, shared x/ao staging) + per-wave 6272-B arena (q|k, later
// aliased by P) = 76 KB -> 2 blocks/CU (4 waves/SIMD). v is transposed
// in-register via ds_bpermute (no LDS). launch_bounds(512,4) caps VGPR<=128.

#define NTOK 49
#define XPAD 264
#define SCALE_F 0.17677669529663687f

typedef _Float16 v8h __attribute__((ext_vector_type(8)));
typedef _Float16 v4h __attribute__((ext_vector_type(4)));
typedef float    v4f __attribute__((ext_vector_type(4)));
typedef int      v4i __attribute__((ext_vector_type(4)));

__device__ __forceinline__ v8h ldsv8(const _Float16* p) { return *(const v8h*)p; }
__device__ __forceinline__ int packh2(float lo, float hi) {
    unsigned short a = __builtin_bit_cast(unsigned short, (_Float16)lo);
    unsigned short b = __builtin_bit_cast(unsigned short, (_Float16)hi);
    return (int)((unsigned)a | ((unsigned)b << 16));
}

// ---------------- prep: f16 weights + float4-packed bias rows ----------------
__global__ void wa_prep(const float* __restrict__ Wq, const float* __restrict__ Wk,
                        const float* __restrict__ Wv, const float* __restrict__ Wp,
                        const float* __restrict__ bias_table, const int* __restrict__ rel_idx,
                        _Float16* __restrict__ wqkv, _Float16* __restrict__ wp,
                        float* __restrict__ biasm2) {
    int t = blockIdx.x * blockDim.x + threadIdx.x;
    const int NW = 768 * 256;
    const int NP = 256 * 256;
    const int NB4 = 8 * NTOK * 16;        // float4 units
    if (t < NW) {
        int n = t >> 8, k = t & 255;
        const float* W = (n < 256) ? Wq : (n < 512 ? Wk : Wv);
        wqkv[t] = (_Float16)W[(n & 255) * 256 + k];
    } else if (t < NW + NP) {
        int u = t - NW;
        wp[u] = (_Float16)Wp[u];
    } else if (t < NW + NP + NB4) {
        int u = t - NW - NP;               // (h*49 + row)*16 + fr
        int fr = u & 15;
        int hr = u >> 4;
        int row = hr % NTOK;
        int h = hr / NTOK;
        float4 v;
        float* vp = &v.x;
        #pragma unroll
        for (int c = 0; c < 4; ++c) {
            int col = fr + 16 * c;
            vp[c] = (col < NTOK) ? bias_table[rel_idx[row * NTOK + col] * 8 + h] : 0.f;
        }
        ((float4*)biasm2)[u] = v;
    }
}

// ---------------- fused window attention ----------------
__global__ __launch_bounds__(512, 4) void wa_fused(
    const float* __restrict__ x,
    const float* __restrict__ bq, const float* __restrict__ bk,
    const float* __restrict__ bv, const float* __restrict__ bp,
    const _Float16* __restrict__ wqkv, const _Float16* __restrict__ wp,
    const float* __restrict__ biasm2, float* __restrict__ out) {

    __shared__ _Float16 xs[NTOK * XPAD];     // 25,872 B  (x staging; ao after attn)
    __shared__ _Float16 arena[8 * 3136];     // 50,176 B  (per-wave: q[49][32]|k[49][32] -> P[49][64])

    const int b    = blockIdx.x;
    const int tid  = threadIdx.x;
    const int wid  = tid >> 6;
    const int lane = tid & 63;
    const int g    = lane >> 4;
    const int fr   = lane & 15;
    const int WB   = wid * 32;               // head-base column

    // ---- phase 1: stage x -> f16 LDS ----
    const float* xb = x + (size_t)b * (NTOK * 256);
    for (int i = tid; i < (NTOK * 256) / 4; i += 512) {
        float4 f = ((const float4*)xb)[i];
        int e = i * 4;
        v4h pk;
        pk[0] = (_Float16)f.x; pk[1] = (_Float16)f.y;
        pk[2] = (_Float16)f.z; pk[3] = (_Float16)f.w;
        *(v4h*)&xs[(e >> 8) * XPAD + (e & 255)] = pk;
    }
    __syncthreads();

    const v4f vzero = {0.f, 0.f, 0.f, 0.f};
    _Float16* wa = &arena[wid * 3136];

    // ---- phase 2v: this head's v, D-layout in regs -> in-register transpose ----
    v4i vT4[2][2];   // [ntd][ks] = v8h B-frag for PV
    {
        v4f av[2][4];
        #pragma unroll
        for (int vl = 0; vl < 2; ++vl)
            #pragma unroll
            for (int mt = 0; mt < 4; ++mt) av[vl][mt] = vzero;
        #pragma unroll
        for (int ks = 0; ks < 8; ++ks) {
            v8h a[4];
            #pragma unroll
            for (int mt = 0; mt < 4; ++mt) {
                int row = mt * 16 + fr; row = row > 48 ? 48 : row;
                a[mt] = ldsv8(&xs[row * XPAD + ks * 32 + g * 8]);
            }
            #pragma unroll
            for (int vl = 0; vl < 2; ++vl) {
                v8h bf = *(const v8h*)&wqkv[(512 + WB + 16 * vl + fr) * 256 + ks * 32 + g * 8];
                #pragma unroll
                for (int mt = 0; mt < 4; ++mt)
                    av[vl][mt] = __builtin_amdgcn_mfma_f32_16x16x32_f16(a[mt], bf, av[vl][mt], 0, 0, 0);
            }
        }
        // bias + zero-pad toks>=49 + pack pairs (r=2p, 2p+1)
        float bvv[2];
        bvv[0] = bv[WB + fr]; bvv[1] = bv[WB + 16 + fr];
        int pkv[2][4][2];
        #pragma unroll
        for (int vl = 0; vl < 2; ++vl)
            #pragma unroll
            for (int mt = 0; mt < 4; ++mt)
                #pragma unroll
                for (int p = 0; p < 2; ++p) {
                    int tl = mt * 16 + 4 * g + 2 * p;
                    float lo = (tl     < NTOK) ? av[vl][mt][2 * p]     + bvv[vl] : 0.f;
                    float hi = (tl + 1 < NTOK) ? av[vl][mt][2 * p + 1] + bvv[vl] : 0.f;
                    pkv[vl][mt][p] = packh2(lo, hi);
                }
        // bpermute transpose: target word w' of B-frag[ntd][ks]:
        //   src lane = 16*((2g + (w'>>1))&3) + fr ; src word pkv[ntd][2ks+(g>>1)][w'&1]
        int addrA = 4 * (16 * ((2 * g) & 3) + fr);       // w' = 0,1
        int addrB = 4 * (16 * ((2 * g + 1) & 3) + fr);   // w' = 2,3
        #pragma unroll
        for (int ntd = 0; ntd < 2; ++ntd)
            #pragma unroll
            for (int ks = 0; ks < 2; ++ks)
                #pragma unroll
                for (int w = 0; w < 4; ++w) {
                    int ad = (w < 2) ? addrA : addrB;
                    int b0 = __builtin_amdgcn_ds_bpermute(ad, pkv[ntd][2 * ks][w & 1]);
                    int b1 = __builtin_amdgcn_ds_bpermute(ad, pkv[ntd][2 * ks + 1][w & 1]);
                    vT4[ntd][ks][w] = (g < 2) ? b0 : b1;
                }
    }

    // ---- phase 2qk: this head's q,k -> swizzled arena (SCALE folded into q) ----
    {
        v4f aq[4][4];    // t: 0,1 = q tiles; 2,3 = k tiles
        #pragma unroll
        for (int t = 0; t < 4; ++t)
            #pragma unroll
            for (int mt = 0; mt < 4; ++mt) aq[t][mt] = vzero;
        #pragma unroll
        for (int ks = 0; ks < 8; ++ks) {
            v8h a[4];
            #pragma unroll
            for (int mt = 0; mt < 4; ++mt) {
                int row = mt * 16 + fr; row = row > 48 ? 48 : row;
                a[mt] = ldsv8(&xs[row * XPAD + ks * 32 + g * 8]);
            }
            #pragma unroll
            for (int t = 0; t < 4; ++t) {
                int n = (t < 2) ? (WB + 16 * t + fr) : (256 + WB + 16 * (t - 2) + fr);
                v8h bf = *(const v8h*)&wqkv[n * 256 + ks * 32 + g * 8];
                #pragma unroll
                for (int mt = 0; mt < 4; ++mt)
                    aq[t][mt] = __builtin_amdgcn_mfma_f32_16x16x32_f16(a[mt], bf, aq[t][mt], 0, 0, 0);
            }
        }
        #pragma unroll
        for (int t = 0; t < 4; ++t) {
            float bias = (t < 2) ? bq[WB + 16 * t + fr] : bk[WB + 16 * (t - 2) + fr];
            float scl  = (t < 2) ? SCALE_F : 1.f;
            int   base = (t < 2) ? 0 : 1568;
            int   d    = 16 * (t & 1) + fr;
            #pragma unroll
            for (int mt = 0; mt < 4; ++mt)
                #pragma unroll
                for (int r = 0; r < 4; ++r) {
                    int tok = mt * 16 + 4 * g + r;
                    if (tok < NTOK) {
                        int ch = (d >> 3) ^ ((tok >> 2) & 3);
                        wa[base + tok * 32 + ch * 8 + (d & 7)] = (_Float16)((aq[t][mt][r] + bias) * scl);
                    }
                }
        }
    }
    __syncthreads();   // xs reads done (ao may overwrite later); arena q/k visible

    // ---- phase 3: QK^T + softmax + P (pre-normalized) ----
    v4f s[4][4];
    {
        v8h ap4[4], bk4[4];
        #pragma unroll
        for (int mt = 0; mt < 4; ++mt) {
            int row = mt * 16 + fr; row = row > 48 ? 48 : row;
            int c = (row >> 2) & 3;
            ap4[mt] = ldsv8(&wa[row * 32 + (g ^ c) * 8]);
        }
        #pragma unroll
        for (int nt = 0; nt < 4; ++nt) {
            int row = nt * 16 + fr; row = row > 48 ? 48 : row;
            int c = (row >> 2) & 3;
            bk4[nt] = ldsv8(&wa[1568 + row * 32 + (g ^ c) * 8]);
        }
        #pragma unroll
        for (int mt = 0; mt < 4; ++mt)
            #pragma unroll
            for (int nt = 0; nt < 4; ++nt)
                s[mt][nt] = __builtin_amdgcn_mfma_f32_16x16x32_f16(ap4[mt], bk4[nt], vzero, 0, 0, 0);
    }
    #pragma unroll
    for (int mt = 0; mt < 4; ++mt) {
        float4 b4[4];
        #pragma unroll
        for (int r = 0; r < 4; ++r) {
            int brow = mt * 16 + 4 * g + r; brow = brow > 48 ? 48 : brow;
            b4[r] = ((const float4*)biasm2)[(wid * NTOK + brow) * 16 + fr];
        }
        #pragma unroll
        for (int r = 0; r < 4; ++r) {
            int row = mt * 16 + 4 * g + r;
            const float* bp4 = &b4[r].x;
            float m = -3.0e38f;
            #pragma unroll
            for (int nt = 0; nt < 4; ++nt) {
                float val = s[mt][nt][r] + bp4[nt];
                if (nt == 3 && fr > 0) val = -1.0e30f;   // col = 48+fr >= 49
                s[mt][nt][r] = val;
                m = fmaxf(m, val);
            }
            #pragma unroll
            for (int off = 1; off < 16; off <<= 1) m = fmaxf(m, __shfl_xor(m, off));
            float sum = 0.f;
            #pragma unroll
            for (int nt = 0; nt < 4; ++nt) {
                float p = __expf(s[mt][nt][r] - m);
                s[mt][nt][r] = p;
                sum += p;
            }
            #pragma unroll
            for (int off = 1; off < 16; off <<= 1) sum += __shfl_xor(sum, off);
            float inv = __builtin_amdgcn_rcpf(sum);
            if (row < NTOK) {
                #pragma unroll
                for (int nt = 0; nt < 4; ++nt) {
                    int col = nt * 16 + fr;
                    wa[row * 64 + (col ^ ((row & 7) << 3))] = (_Float16)(s[mt][nt][r] * inv);
                }
            }
        }
    }
    // in-wave P write -> read ordering (same arena bytes as q/k)
    asm volatile("s_waitcnt lgkmcnt(0)" ::: "memory");
    __builtin_amdgcn_sched_barrier(0);

    // ---- phase 3b: PV (v from registers) ----
    {
        v4f o[4][2];
        #pragma unroll
        for (int mt = 0; mt < 4; ++mt) { o[mt][0] = vzero; o[mt][1] = vzero; }
        #pragma unroll
        for (int mt = 0; mt < 4; ++mt) {
            int row = mt * 16 + fr; row = row > 48 ? 48 : row;
            int r7 = row & 7;
            #pragma unroll
            for (int ks = 0; ks < 2; ++ks) {
                v8h ap = ldsv8(&wa[row * 64 + ((4 * ks + g) ^ r7) * 8]);
                #pragma unroll
                for (int ntd = 0; ntd < 2; ++ntd) {
                    v8h bvv = __builtin_bit_cast(v8h, vT4[ntd][ks]);
                    o[mt][ntd] = __builtin_amdgcn_mfma_f32_16x16x32_f16(ap, bvv, o[mt][ntd], 0, 0, 0);
                }
            }
        }
        // ao -> xs (cols WB..WB+31), P was pre-normalized: no epilogue scaling
        #pragma unroll
        for (int mt = 0; mt < 4; ++mt)
            #pragma unroll
            for (int r = 0; r < 4; ++r) {
                int tok = mt * 16 + 4 * g + r;
                if (tok < NTOK) {
                    #pragma unroll
                    for (int ntd = 0; ntd < 2; ++ntd)
                        xs[tok * XPAD + WB + 16 * ntd + fr] = (_Float16)o[mt][ntd][r];
                }
            }
    }
    __syncthreads();   // all heads' ao staged

    // ---- phase 4: output projection ----
    {
        v4f acc[2][4];
        #pragma unroll
        for (int i = 0; i < 2; ++i)
            #pragma unroll
            for (int j = 0; j < 4; ++j) acc[i][j] = vzero;
        #pragma unroll
        for (int ks = 0; ks < 8; ++ks) {
            v8h a[4];
            #pragma unroll
            for (int mt = 0; mt < 4; ++mt) {
                int row = mt * 16 + fr; row = row > 48 ? 48 : row;
                a[mt] = ldsv8(&xs[row * XPAD + ks * 32 + g * 8]);
            }
            #pragma unroll
            for (int ntl = 0; ntl < 2; ++ntl) {
                int n = (wid * 2 + ntl) * 16 + fr;
                v8h bf = *(const v8h*)&wp[n * 256 + ks * 32 + g * 8];
                #pragma unroll
                for (int mt = 0; mt < 4; ++mt)
                    acc[ntl][mt] = __builtin_amdgcn_mfma_f32_16x16x32_f16(a[mt], bf, acc[ntl][mt], 0, 0, 0);
            }
        }
        float* ob = out + (size_t)b * (NTOK * 256);
        #pragma unroll
        for (int ntl = 0; ntl < 2; ++ntl) {
            int n = (wid * 2 + ntl) * 16 + fr;
            float bpn = bp[n];
            #pragma unroll
            for (int mt = 0; mt < 4; ++mt)
                #pragma unroll
                for (int r = 0; r < 4; ++r) {
                    int tok = mt * 16 + 4 * g + r;
                    if (tok < NTOK) ob[tok * 256 + n] = acc[ntl][mt][r] + bpn;
                }
        }
    }
}

extern "C" void kernel_launch(void* const* d_in, const int* in_sizes, int n_in,
                              void* d_out, int out_size, void* d_ws, size_t ws_size,
                              hipStream_t stream) {
    const float* x          = (const float*)d_in[0];
    const float* bias_table = (const float*)d_in[1];
    const float* Wq         = (const float*)d_in[2];
    const float* bq         = (const float*)d_in[3];
    const float* Wk         = (const float*)d_in[4];
    const float* bk         = (const float*)d_in[5];
    const float* Wv         = (const float*)d_in[6];
    const float* bv         = (const float*)d_in[7];
    const float* Wp         = (const float*)d_in[8];
    const float* bp         = (const float*)d_in[9];
    const int*   rel_idx    = (const int*)d_in[10];
    float* out = (float*)d_out;

    // ws: wqkv f16 [768*256] | wp f16 [256*256] | biasm2 f32 [8*49*16*4]  (~610 KB)
    _Float16* wqkv  = (_Float16*)d_ws;
    _Float16* wp    = wqkv + 768 * 256;
    float*    biasm2 = (float*)(wp + 256 * 256);

    const int TOT = 768 * 256 + 256 * 256 + 8 * NTOK * 16;
    wa_prep<<<(TOT + 255) / 256, 256, 0, stream>>>(Wq, Wk, Wv, Wp, bias_table, rel_idx,
                                                   wqkv, wp, biasm2);
    wa_fused<<<4096, 512, 0, stream>>>(x, bq, bk, bv, bp, wqkv, wp, biasm2, out);
}

// Round 3
// 662.103 us; speedup vs baseline: 1.1073x; 1.1073x over previous
//
#include <hip/hip_runtime.h>

// WindowAttention fused kernel v3 for MI355X (gfx950).
// B=4096 windows, N=49, C=256, H=8, hd=32. fp32 in/out, f16 MFMA inside.
//
// One block = one window (512 thr = 8 waves), wave w owns head w end-to-end.
// LDS: xs (25.9 KB, x/ao staging) + per-wave 6272-B arena (q|k, aliased by P)
// = 76 KB -> 2 blocks/CU. v transposed in-register via ds_bpermute (no LDS).
// v3: q and k projection split into two passes (32 accums each, not 64) and
// bias loads inlined, to fit the 128-reg cap of launch_bounds(512,4) with NO
// scratch spill (r2 spilled ~1.6 GB to scratch and regressed).

#define NTOK 49
#define XPAD 264
#define SCALE_F 0.17677669529663687f

typedef _Float16 v8h __attribute__((ext_vector_type(8)));
typedef _Float16 v4h __attribute__((ext_vector_type(4)));
typedef float    v4f __attribute__((ext_vector_type(4)));
typedef int      v4i __attribute__((ext_vector_type(4)));

__device__ __forceinline__ v8h ldsv8(const _Float16* p) { return *(const v8h*)p; }
__device__ __forceinline__ int packh2(float lo, float hi) {
    unsigned short a = __builtin_bit_cast(unsigned short, (_Float16)lo);
    unsigned short b = __builtin_bit_cast(unsigned short, (_Float16)hi);
    return (int)((unsigned)a | ((unsigned)b << 16));
}

// ---------------- prep: f16 weights + float4-packed bias rows ----------------
__global__ void wa_prep(const float* __restrict__ Wq, const float* __restrict__ Wk,
                        const float* __restrict__ Wv, const float* __restrict__ Wp,
                        const float* __restrict__ bias_table, const int* __restrict__ rel_idx,
                        _Float16* __restrict__ wqkv, _Float16* __restrict__ wp,
                        float* __restrict__ biasm2) {
    int t = blockIdx.x * blockDim.x + threadIdx.x;
    const int NW = 768 * 256;
    const int NP = 256 * 256;
    const int NB4 = 8 * NTOK * 16;        // float4 units
    if (t < NW) {
        int n = t >> 8, k = t & 255;
        const float* W = (n < 256) ? Wq : (n < 512 ? Wk : Wv);
        wqkv[t] = (_Float16)W[(n & 255) * 256 + k];
    } else if (t < NW + NP) {
        int u = t - NW;
        wp[u] = (_Float16)Wp[u];
    } else if (t < NW + NP + NB4) {
        int u = t - NW - NP;               // (h*49 + row)*16 + fr
        int fr = u & 15;
        int hr = u >> 4;
        int row = hr % NTOK;
        int h = hr / NTOK;
        float4 v;
        float* vp = &v.x;
        #pragma unroll
        for (int c = 0; c < 4; ++c) {
            int col = fr + 16 * c;
            vp[c] = (col < NTOK) ? bias_table[rel_idx[row * NTOK + col] * 8 + h] : 0.f;
        }
        ((float4*)biasm2)[u] = v;
    }
}

// ---------------- fused window attention ----------------
__global__ __launch_bounds__(512, 4) void wa_fused(
    const float* __restrict__ x,
    const float* __restrict__ bq, const float* __restrict__ bk,
    const float* __restrict__ bv, const float* __restrict__ bp,
    const _Float16* __restrict__ wqkv, const _Float16* __restrict__ wp,
    const float* __restrict__ biasm2, float* __restrict__ out) {

    __shared__ _Float16 xs[NTOK * XPAD];     // 25,872 B  (x staging; ao after attn)
    __shared__ _Float16 arena[8 * 3136];     // 50,176 B  (per-wave: q[49][32]|k[49][32] -> P[49][64])

    const int b    = blockIdx.x;
    const int tid  = threadIdx.x;
    const int wid  = tid >> 6;
    const int lane = tid & 63;
    const int g    = lane >> 4;
    const int fr   = lane & 15;
    const int WB   = wid * 32;               // head-base column

    // ---- phase 1: stage x -> f16 LDS ----
    const float* xb = x + (size_t)b * (NTOK * 256);
    for (int i = tid; i < (NTOK * 256) / 4; i += 512) {
        float4 f = ((const float4*)xb)[i];
        int e = i * 4;
        v4h pk;
        pk[0] = (_Float16)f.x; pk[1] = (_Float16)f.y;
        pk[2] = (_Float16)f.z; pk[3] = (_Float16)f.w;
        *(v4h*)&xs[(e >> 8) * XPAD + (e & 255)] = pk;
    }
    __syncthreads();

    const v4f vzero = {0.f, 0.f, 0.f, 0.f};
    _Float16* wa = &arena[wid * 3136];

    // ---- phase 2v: this head's v, D-layout in regs -> in-register transpose ----
    v4i vT4[2][2];   // [ntd][ks] = v8h B-frag for PV
    {
        v4f av[2][4];
        #pragma unroll
        for (int vl = 0; vl < 2; ++vl)
            #pragma unroll
            for (int mt = 0; mt < 4; ++mt) av[vl][mt] = vzero;
        #pragma unroll
        for (int ks = 0; ks < 8; ++ks) {
            v8h a[4];
            #pragma unroll
            for (int mt = 0; mt < 4; ++mt) {
                int row = mt * 16 + fr; row = row > 48 ? 48 : row;
                a[mt] = ldsv8(&xs[row * XPAD + ks * 32 + g * 8]);
            }
            #pragma unroll
            for (int vl = 0; vl < 2; ++vl) {
                v8h bf = *(const v8h*)&wqkv[(512 + WB + 16 * vl + fr) * 256 + ks * 32 + g * 8];
                #pragma unroll
                for (int mt = 0; mt < 4; ++mt)
                    av[vl][mt] = __builtin_amdgcn_mfma_f32_16x16x32_f16(a[mt], bf, av[vl][mt], 0, 0, 0);
            }
        }
        // bias + zero-pad toks>=49 + pack pairs (r=2p, 2p+1)
        float bvv[2];
        bvv[0] = bv[WB + fr]; bvv[1] = bv[WB + 16 + fr];
        int pkv[2][4][2];
        #pragma unroll
        for (int vl = 0; vl < 2; ++vl)
            #pragma unroll
            for (int mt = 0; mt < 4; ++mt)
                #pragma unroll
                for (int p = 0; p < 2; ++p) {
                    int tl = mt * 16 + 4 * g + 2 * p;
                    float lo = (tl     < NTOK) ? av[vl][mt][2 * p]     + bvv[vl] : 0.f;
                    float hi = (tl + 1 < NTOK) ? av[vl][mt][2 * p + 1] + bvv[vl] : 0.f;
                    pkv[vl][mt][p] = packh2(lo, hi);
                }
        // bpermute transpose: target word w' of B-frag[ntd][ks]:
        //   src lane = 16*((2g + (w'>>1))&3) + fr ; src word pkv[ntd][2ks+(g>>1)][w'&1]
        int addrA = 4 * (16 * ((2 * g) & 3) + fr);       // w' = 0,1
        int addrB = 4 * (16 * ((2 * g + 1) & 3) + fr);   // w' = 2,3
        #pragma unroll
        for (int ntd = 0; ntd < 2; ++ntd)
            #pragma unroll
            for (int ks = 0; ks < 2; ++ks)
                #pragma unroll
                for (int w = 0; w < 4; ++w) {
                    int ad = (w < 2) ? addrA : addrB;
                    int b0 = __builtin_amdgcn_ds_bpermute(ad, pkv[ntd][2 * ks][w & 1]);
                    int b1 = __builtin_amdgcn_ds_bpermute(ad, pkv[ntd][2 * ks + 1][w & 1]);
                    vT4[ntd][ks][w] = (g < 2) ? b0 : b1;
                }
    }

    // ---- phase 2q / 2k: two low-pressure passes (32 accums each) ----
    #pragma unroll
    for (int qk = 0; qk < 2; ++qk) {
        v4f acc[2][4];
        #pragma unroll
        for (int t = 0; t < 2; ++t)
            #pragma unroll
            for (int mt = 0; mt < 4; ++mt) acc[t][mt] = vzero;
        #pragma unroll
        for (int ks = 0; ks < 8; ++ks) {
            v8h a[4];
            #pragma unroll
            for (int mt = 0; mt < 4; ++mt) {
                int row = mt * 16 + fr; row = row > 48 ? 48 : row;
                a[mt] = ldsv8(&xs[row * XPAD + ks * 32 + g * 8]);
            }
            #pragma unroll
            for (int t = 0; t < 2; ++t) {
                int n = 256 * qk + WB + 16 * t + fr;
                v8h bf = *(const v8h*)&wqkv[n * 256 + ks * 32 + g * 8];
                #pragma unroll
                for (int mt = 0; mt < 4; ++mt)
                    acc[t][mt] = __builtin_amdgcn_mfma_f32_16x16x32_f16(a[mt], bf, acc[t][mt], 0, 0, 0);
            }
        }
        #pragma unroll
        for (int t = 0; t < 2; ++t) {
            float bias = qk ? bk[WB + 16 * t + fr] : bq[WB + 16 * t + fr];
            float scl  = qk ? 1.f : SCALE_F;
            int   base = qk ? 1568 : 0;
            int   d    = 16 * t + fr;
            #pragma unroll
            for (int mt = 0; mt < 4; ++mt)
                #pragma unroll
                for (int r = 0; r < 4; ++r) {
                    int tok = mt * 16 + 4 * g + r;
                    if (tok < NTOK) {
                        int ch = (d >> 3) ^ ((tok >> 2) & 3);
                        wa[base + tok * 32 + ch * 8 + (d & 7)] = (_Float16)((acc[t][mt][r] + bias) * scl);
                    }
                }
        }
    }
    __syncthreads();   // all waves done reading xs; arena q/k visible in-wave

    // ---- phase 3: QK^T + softmax + P (pre-normalized) ----
    v4f s[4][4];
    {
        v8h ap4[4], bk4[4];
        #pragma unroll
        for (int mt = 0; mt < 4; ++mt) {
            int row = mt * 16 + fr; row = row > 48 ? 48 : row;
            int c = (row >> 2) & 3;
            ap4[mt] = ldsv8(&wa[row * 32 + (g ^ c) * 8]);
        }
        #pragma unroll
        for (int nt = 0; nt < 4; ++nt) {
            int row = nt * 16 + fr; row = row > 48 ? 48 : row;
            int c = (row >> 2) & 3;
            bk4[nt] = ldsv8(&wa[1568 + row * 32 + (g ^ c) * 8]);
        }
        #pragma unroll
        for (int mt = 0; mt < 4; ++mt)
            #pragma unroll
            for (int nt = 0; nt < 4; ++nt)
                s[mt][nt] = __builtin_amdgcn_mfma_f32_16x16x32_f16(ap4[mt], bk4[nt], vzero, 0, 0, 0);
    }
    #pragma unroll
    for (int mt = 0; mt < 4; ++mt) {
        #pragma unroll
        for (int r = 0; r < 4; ++r) {
            int row  = mt * 16 + 4 * g + r;
            int brow = row > 48 ? 48 : row;
            float4 b4 = ((const float4*)biasm2)[(wid * NTOK + brow) * 16 + fr];
            const float* bp4 = &b4.x;
            float m = -3.0e38f;
            #pragma unroll
            for (int nt = 0; nt < 4; ++nt) {
                float val = s[mt][nt][r] + bp4[nt];
                if (nt == 3 && fr > 0) val = -1.0e30f;   // col = 48+fr >= 49
                s[mt][nt][r] = val;
                m = fmaxf(m, val);
            }
            #pragma unroll
            for (int off = 1; off < 16; off <<= 1) m = fmaxf(m, __shfl_xor(m, off));
            float sum = 0.f;
            #pragma unroll
            for (int nt = 0; nt < 4; ++nt) {
                float p = __expf(s[mt][nt][r] - m);
                s[mt][nt][r] = p;
                sum += p;
            }
            #pragma unroll
            for (int off = 1; off < 16; off <<= 1) sum += __shfl_xor(sum, off);
            float inv = __builtin_amdgcn_rcpf(sum);
            if (row < NTOK) {
                #pragma unroll
                for (int nt = 0; nt < 4; ++nt) {
                    int col = nt * 16 + fr;
                    wa[row * 64 + (col ^ ((row & 7) << 3))] = (_Float16)(s[mt][nt][r] * inv);
                }
            }
        }
    }
    // in-wave P write -> read ordering (same arena bytes as q/k)
    asm volatile("s_waitcnt lgkmcnt(0)" ::: "memory");
    __builtin_amdgcn_sched_barrier(0);

    // ---- phase 3b: PV (v from registers) ----
    {
        v4f o[4][2];
        #pragma unroll
        for (int mt = 0; mt < 4; ++mt) { o[mt][0] = vzero; o[mt][1] = vzero; }
        #pragma unroll
        for (int mt = 0; mt < 4; ++mt) {
            int row = mt * 16 + fr; row = row > 48 ? 48 : row;
            int r7 = row & 7;
            #pragma unroll
            for (int ks = 0; ks < 2; ++ks) {
                v8h ap = ldsv8(&wa[row * 64 + ((4 * ks + g) ^ r7) * 8]);
                #pragma unroll
                for (int ntd = 0; ntd < 2; ++ntd) {
                    v8h bvv = __builtin_bit_cast(v8h, vT4[ntd][ks]);
                    o[mt][ntd] = __builtin_amdgcn_mfma_f32_16x16x32_f16(ap, bvv, o[mt][ntd], 0, 0, 0);
                }
            }
        }
        // ao -> xs (cols WB..WB+31), P was pre-normalized: no epilogue scaling
        #pragma unroll
        for (int mt = 0; mt < 4; ++mt)
            #pragma unroll
            for (int r = 0; r < 4; ++r) {
                int tok = mt * 16 + 4 * g + r;
                if (tok < NTOK) {
                    #pragma unroll
                    for (int ntd = 0; ntd < 2; ++ntd)
                        xs[tok * XPAD + WB + 16 * ntd + fr] = (_Float16)o[mt][ntd][r];
                }
            }
    }
    __syncthreads();   // all heads' ao staged

    // ---- phase 4: output projection ----
    {
        v4f acc[2][4];
        #pragma unroll
        for (int i = 0; i < 2; ++i)
            #pragma unroll
            for (int j = 0; j < 4; ++j) acc[i][j] = vzero;
        #pragma unroll
        for (int ks = 0; ks < 8; ++ks) {
            v8h a[4];
            #pragma unroll
            for (int mt = 0; mt < 4; ++mt) {
                int row = mt * 16 + fr; row = row > 48 ? 48 : row;
                a[mt] = ldsv8(&xs[row * XPAD + ks * 32 + g * 8]);
            }
            #pragma unroll
            for (int ntl = 0; ntl < 2; ++ntl) {
                int n = (wid * 2 + ntl) * 16 + fr;
                v8h bf = *(const v8h*)&wp[n * 256 + ks * 32 + g * 8];
                #pragma unroll
                for (int mt = 0; mt < 4; ++mt)
                    acc[ntl][mt] = __builtin_amdgcn_mfma_f32_16x16x32_f16(a[mt], bf, acc[ntl][mt], 0, 0, 0);
            }
        }
        float* ob = out + (size_t)b * (NTOK * 256);
        #pragma unroll
        for (int ntl = 0; ntl < 2; ++ntl) {
            int n = (wid * 2 + ntl) * 16 + fr;
            float bpn = bp[n];
            #pragma unroll
            for (int mt = 0; mt < 4; ++mt)
                #pragma unroll
                for (int r = 0; r < 4; ++r) {
                    int tok = mt * 16 + 4 * g + r;
                    if (tok < NTOK) ob[tok * 256 + n] = acc[ntl][mt][r] + bpn;
                }
        }
    }
}

extern "C" void kernel_launch(void* const* d_in, const int* in_sizes, int n_in,
                              void* d_out, int out_size, void* d_ws, size_t ws_size,
                              hipStream_t stream) {
    const float* x          = (const float*)d_in[0];
    const float* bias_table = (const float*)d_in[1];
    const float* Wq         = (const float*)d_in[2];
    const float* bq         = (const float*)d_in[3];
    const float* Wk         = (const float*)d_in[4];
    const float* bk         = (const float*)d_in[5];
    const float* Wv         = (const float*)d_in[6];
    const float* bv         = (const float*)d_in[7];
    const float* Wp         = (const float*)d_in[8];
    const float* bp         = (const float*)d_in[9];
    const int*   rel_idx    = (const int*)d_in[10];
    float* out = (float*)d_out;

    // ws: wqkv f16 [768*256] | wp f16 [256*256] | biasm2 f32 [8*49*16*4]  (~610 KB)
    _Float16* wqkv  = (_Float16*)d_ws;
    _Float16* wp    = wqkv + 768 * 256;
    float*    biasm2 = (float*)(wp + 256 * 256);

    const int TOT = 768 * 256 + 256 * 256 + 8 * NTOK * 16;
    wa_prep<<<(TOT + 255) / 256, 256, 0, stream>>>(Wq, Wk, Wv, Wp, bias_table, rel_idx,
                                                   wqkv, wp, biasm2);
    wa_fused<<<4096, 512, 0, stream>>>(x, bq, bk, bv, bp, wqkv, wp, biasm2, out);
}

// Round 4
// 444.640 us; speedup vs baseline: 1.6489x; 1.4891x over previous
//
#include <hip/hip_runtime.h>

// WindowAttention fused kernel v4 for MI355X (gfx950).
// B=4096 windows, N=49, C=256, H=8, hd=32. fp32 in/out, f16 MFMA inside.
//
// One block = one window (512 thr = 8 waves), wave w owns head w end-to-end.
// LDS: xs (25.9 KB, x/ao staging) + per-wave 6272-B arena (q|k, aliased by P)
// = 76 KB -> 2 blocks/CU. v transposed in-register via ds_bpermute (no LDS).
// v4: softmax processed per-16-row-tile (s[4] = 16 regs instead of s[4][4] =
// 64) with all q/k fragments preloaded before P overwrites the arena, plus
// sched_barrier(0) fences between phases to contain register pressure under
// the 128-reg cap of launch_bounds(512,4). r2/r3 spilled ~1.6 GB to scratch.

#define NTOK 49
#define XPAD 264
#define SCALE_F 0.17677669529663687f

typedef _Float16 v8h __attribute__((ext_vector_type(8)));
typedef _Float16 v4h __attribute__((ext_vector_type(4)));
typedef float    v4f __attribute__((ext_vector_type(4)));
typedef int      v4i __attribute__((ext_vector_type(4)));

__device__ __forceinline__ v8h ldsv8(const _Float16* p) { return *(const v8h*)p; }
__device__ __forceinline__ int packh2(float lo, float hi) {
    unsigned short a = __builtin_bit_cast(unsigned short, (_Float16)lo);
    unsigned short b = __builtin_bit_cast(unsigned short, (_Float16)hi);
    return (int)((unsigned)a | ((unsigned)b << 16));
}

// ---------------- prep: f16 weights + float4-packed bias rows ----------------
__global__ void wa_prep(const float* __restrict__ Wq, const float* __restrict__ Wk,
                        const float* __restrict__ Wv, const float* __restrict__ Wp,
                        const float* __restrict__ bias_table, const int* __restrict__ rel_idx,
                        _Float16* __restrict__ wqkv, _Float16* __restrict__ wp,
                        float* __restrict__ biasm2) {
    int t = blockIdx.x * blockDim.x + threadIdx.x;
    const int NW = 768 * 256;
    const int NP = 256 * 256;
    const int NB4 = 8 * NTOK * 16;        // float4 units
    if (t < NW) {
        int n = t >> 8, k = t & 255;
        const float* W = (n < 256) ? Wq : (n < 512 ? Wk : Wv);
        wqkv[t] = (_Float16)W[(n & 255) * 256 + k];
    } else if (t < NW + NP) {
        int u = t - NW;
        wp[u] = (_Float16)Wp[u];
    } else if (t < NW + NP + NB4) {
        int u = t - NW - NP;               // (h*49 + row)*16 + fr
        int fr = u & 15;
        int hr = u >> 4;
        int row = hr % NTOK;
        int h = hr / NTOK;
        float4 v;
        float* vp = &v.x;
        #pragma unroll
        for (int c = 0; c < 4; ++c) {
            int col = fr + 16 * c;
            vp[c] = (col < NTOK) ? bias_table[rel_idx[row * NTOK + col] * 8 + h] : 0.f;
        }
        ((float4*)biasm2)[u] = v;
    }
}

// ---------------- fused window attention ----------------
__global__ __launch_bounds__(512, 4) void wa_fused(
    const float* __restrict__ x,
    const float* __restrict__ bq, const float* __restrict__ bk,
    const float* __restrict__ bv, const float* __restrict__ bp,
    const _Float16* __restrict__ wqkv, const _Float16* __restrict__ wp,
    const float* __restrict__ biasm2, float* __restrict__ out) {

    __shared__ _Float16 xs[NTOK * XPAD];     // 25,872 B  (x staging; ao after attn)
    __shared__ _Float16 arena[8 * 3136];     // 50,176 B  (per-wave: q[49][32]|k[49][32] -> P[49][64])

    const int b    = blockIdx.x;
    const int tid  = threadIdx.x;
    const int wid  = tid >> 6;
    const int lane = tid & 63;
    const int g    = lane >> 4;
    const int fr   = lane & 15;
    const int WB   = wid * 32;               // head-base column

    // ---- phase 1: stage x -> f16 LDS ----
    const float* xb = x + (size_t)b * (NTOK * 256);
    for (int i = tid; i < (NTOK * 256) / 4; i += 512) {
        float4 f = ((const float4*)xb)[i];
        int e = i * 4;
        v4h pk;
        pk[0] = (_Float16)f.x; pk[1] = (_Float16)f.y;
        pk[2] = (_Float16)f.z; pk[3] = (_Float16)f.w;
        *(v4h*)&xs[(e >> 8) * XPAD + (e & 255)] = pk;
    }
    __syncthreads();

    const v4f vzero = {0.f, 0.f, 0.f, 0.f};
    _Float16* wa = &arena[wid * 3136];

    // ---- phase 2v: this head's v, D-layout in regs -> in-register transpose ----
    v4i vT4[2][2];   // [ntd][ks] = v8h B-frag for PV
    {
        v4f av[2][4];
        #pragma unroll
        for (int vl = 0; vl < 2; ++vl)
            #pragma unroll
            for (int mt = 0; mt < 4; ++mt) av[vl][mt] = vzero;
        #pragma unroll
        for (int ks = 0; ks < 8; ++ks) {
            v8h a[4];
            #pragma unroll
            for (int mt = 0; mt < 4; ++mt) {
                int row = mt * 16 + fr; row = row > 48 ? 48 : row;
                a[mt] = ldsv8(&xs[row * XPAD + ks * 32 + g * 8]);
            }
            #pragma unroll
            for (int vl = 0; vl < 2; ++vl) {
                v8h bf = *(const v8h*)&wqkv[(512 + WB + 16 * vl + fr) * 256 + ks * 32 + g * 8];
                #pragma unroll
                for (int mt = 0; mt < 4; ++mt)
                    av[vl][mt] = __builtin_amdgcn_mfma_f32_16x16x32_f16(a[mt], bf, av[vl][mt], 0, 0, 0);
            }
        }
        // bias + zero-pad toks>=49 + pack pairs (r=2p, 2p+1)
        float bvv[2];
        bvv[0] = bv[WB + fr]; bvv[1] = bv[WB + 16 + fr];
        int pkv[2][4][2];
        #pragma unroll
        for (int vl = 0; vl < 2; ++vl)
            #pragma unroll
            for (int mt = 0; mt < 4; ++mt)
                #pragma unroll
                for (int p = 0; p < 2; ++p) {
                    int tl = mt * 16 + 4 * g + 2 * p;
                    float lo = (tl     < NTOK) ? av[vl][mt][2 * p]     + bvv[vl] : 0.f;
                    float hi = (tl + 1 < NTOK) ? av[vl][mt][2 * p + 1] + bvv[vl] : 0.f;
                    pkv[vl][mt][p] = packh2(lo, hi);
                }
        // bpermute transpose: target word w' of B-frag[ntd][ks]:
        //   src lane = 16*((2g + (w'>>1))&3) + fr ; src word pkv[ntd][2ks+(g>>1)][w'&1]
        int addrA = 4 * (16 * ((2 * g) & 3) + fr);       // w' = 0,1
        int addrB = 4 * (16 * ((2 * g + 1) & 3) + fr);   // w' = 2,3
        #pragma unroll
        for (int ntd = 0; ntd < 2; ++ntd)
            #pragma unroll
            for (int ks = 0; ks < 2; ++ks)
                #pragma unroll
                for (int w = 0; w < 4; ++w) {
                    int ad = (w < 2) ? addrA : addrB;
                    int b0 = __builtin_amdgcn_ds_bpermute(ad, pkv[ntd][2 * ks][w & 1]);
                    int b1 = __builtin_amdgcn_ds_bpermute(ad, pkv[ntd][2 * ks + 1][w & 1]);
                    vT4[ntd][ks][w] = (g < 2) ? b0 : b1;
                }
    }
    __builtin_amdgcn_sched_barrier(0);   // seal phase 2v live set (av/pkv dead here)

    // ---- phase 2q / 2k: two low-pressure passes (32 accums each) ----
    #pragma unroll
    for (int qk = 0; qk < 2; ++qk) {
        v4f acc[2][4];
        #pragma unroll
        for (int t = 0; t < 2; ++t)
            #pragma unroll
            for (int mt = 0; mt < 4; ++mt) acc[t][mt] = vzero;
        #pragma unroll
        for (int ks = 0; ks < 8; ++ks) {
            v8h a[4];
            #pragma unroll
            for (int mt = 0; mt < 4; ++mt) {
                int row = mt * 16 + fr; row = row > 48 ? 48 : row;
                a[mt] = ldsv8(&xs[row * XPAD + ks * 32 + g * 8]);
            }
            #pragma unroll
            for (int t = 0; t < 2; ++t) {
                int n = 256 * qk + WB + 16 * t + fr;
                v8h bf = *(const v8h*)&wqkv[n * 256 + ks * 32 + g * 8];
                #pragma unroll
                for (int mt = 0; mt < 4; ++mt)
                    acc[t][mt] = __builtin_amdgcn_mfma_f32_16x16x32_f16(a[mt], bf, acc[t][mt], 0, 0, 0);
            }
        }
        #pragma unroll
        for (int t = 0; t < 2; ++t) {
            float bias = qk ? bk[WB + 16 * t + fr] : bq[WB + 16 * t + fr];
            float scl  = qk ? 1.f : SCALE_F;
            int   base = qk ? 1568 : 0;
            int   d    = 16 * t + fr;
            #pragma unroll
            for (int mt = 0; mt < 4; ++mt)
                #pragma unroll
                for (int r = 0; r < 4; ++r) {
                    int tok = mt * 16 + 4 * g + r;
                    if (tok < NTOK) {
                        int ch = (d >> 3) ^ ((tok >> 2) & 3);
                        wa[base + tok * 32 + ch * 8 + (d & 7)] = (_Float16)((acc[t][mt][r] + bias) * scl);
                    }
                }
        }
        __builtin_amdgcn_sched_barrier(0);   // seal this pass's accumulators
    }
    __syncthreads();   // all waves done reading xs; arena q/k visible in-wave

    // ---- phase 3: QK^T + softmax + P (pre-normalized), per-mt to cap regs ----
    {
        // preload ALL q/k fragments: P writes below alias the same arena bytes
        v8h ap4[4], bk4[4];
        #pragma unroll
        for (int t = 0; t < 4; ++t) {
            int row = t * 16 + fr; row = row > 48 ? 48 : row;
            int c = (row >> 2) & 3;
            ap4[t] = ldsv8(&wa[row * 32 + (g ^ c) * 8]);
            bk4[t] = ldsv8(&wa[1568 + row * 32 + (g ^ c) * 8]);
        }
        asm volatile("s_waitcnt lgkmcnt(0)" ::: "memory");   // frags in regs before overwrite
        __builtin_amdgcn_sched_barrier(0);

        #pragma unroll
        for (int mt = 0; mt < 4; ++mt) {
            v4f s[4];
            #pragma unroll
            for (int nt = 0; nt < 4; ++nt)
                s[nt] = __builtin_amdgcn_mfma_f32_16x16x32_f16(ap4[mt], bk4[nt], vzero, 0, 0, 0);
            #pragma unroll
            for (int r = 0; r < 4; ++r) {
                int row  = mt * 16 + 4 * g + r;
                int brow = row > 48 ? 48 : row;
                float4 b4 = ((const float4*)biasm2)[(wid * NTOK + brow) * 16 + fr];
                const float* bp4 = &b4.x;
                float m = -3.0e38f;
                #pragma unroll
                for (int nt = 0; nt < 4; ++nt) {
                    float val = s[nt][r] + bp4[nt];
                    if (nt == 3 && fr > 0) val = -1.0e30f;   // col = 48+fr >= 49
                    s[nt][r] = val;
                    m = fmaxf(m, val);
                }
                #pragma unroll
                for (int off = 1; off < 16; off <<= 1) m = fmaxf(m, __shfl_xor(m, off));
                float sum = 0.f;
                #pragma unroll
                for (int nt = 0; nt < 4; ++nt) {
                    float p = __expf(s[nt][r] - m);
                    s[nt][r] = p;
                    sum += p;
                }
                #pragma unroll
                for (int off = 1; off < 16; off <<= 1) sum += __shfl_xor(sum, off);
                float inv = __builtin_amdgcn_rcpf(sum);
                if (row < NTOK) {
                    #pragma unroll
                    for (int nt = 0; nt < 4; ++nt) {
                        int col = nt * 16 + fr;
                        wa[row * 64 + (col ^ ((row & 7) << 3))] = (_Float16)(s[nt][r] * inv);
                    }
                }
            }
        }
    }
    // in-wave P write -> read ordering (same arena bytes as q/k)
    asm volatile("s_waitcnt lgkmcnt(0)" ::: "memory");
    __builtin_amdgcn_sched_barrier(0);

    // ---- phase 3b: PV (v from registers) ----
    {
        v4f o[4][2];
        #pragma unroll
        for (int mt = 0; mt < 4; ++mt) { o[mt][0] = vzero; o[mt][1] = vzero; }
        #pragma unroll
        for (int mt = 0; mt < 4; ++mt) {
            int row = mt * 16 + fr; row = row > 48 ? 48 : row;
            int r7 = row & 7;
            #pragma unroll
            for (int ks = 0; ks < 2; ++ks) {
                v8h ap = ldsv8(&wa[row * 64 + ((4 * ks + g) ^ r7) * 8]);
                #pragma unroll
                for (int ntd = 0; ntd < 2; ++ntd) {
                    v8h bvv = __builtin_bit_cast(v8h, vT4[ntd][ks]);
                    o[mt][ntd] = __builtin_amdgcn_mfma_f32_16x16x32_f16(ap, bvv, o[mt][ntd], 0, 0, 0);
                }
            }
        }
        // ao -> xs (cols WB..WB+31), P was pre-normalized: no epilogue scaling
        #pragma unroll
        for (int mt = 0; mt < 4; ++mt)
            #pragma unroll
            for (int r = 0; r < 4; ++r) {
                int tok = mt * 16 + 4 * g + r;
                if (tok < NTOK) {
                    #pragma unroll
                    for (int ntd = 0; ntd < 2; ++ntd)
                        xs[tok * XPAD + WB + 16 * ntd + fr] = (_Float16)o[mt][ntd][r];
                }
            }
    }
    __syncthreads();   // all heads' ao staged

    // ---- phase 4: output projection ----
    {
        v4f acc[2][4];
        #pragma unroll
        for (int i = 0; i < 2; ++i)
            #pragma unroll
            for (int j = 0; j < 4; ++j) acc[i][j] = vzero;
        #pragma unroll
        for (int ks = 0; ks < 8; ++ks) {
            v8h a[4];
            #pragma unroll
            for (int mt = 0; mt < 4; ++mt) {
                int row = mt * 16 + fr; row = row > 48 ? 48 : row;
                a[mt] = ldsv8(&xs[row * XPAD + ks * 32 + g * 8]);
            }
            #pragma unroll
            for (int ntl = 0; ntl < 2; ++ntl) {
                int n = (wid * 2 + ntl) * 16 + fr;
                v8h bf = *(const v8h*)&wp[n * 256 + ks * 32 + g * 8];
                #pragma unroll
                for (int mt = 0; mt < 4; ++mt)
                    acc[ntl][mt] = __builtin_amdgcn_mfma_f32_16x16x32_f16(a[mt], bf, acc[ntl][mt], 0, 0, 0);
            }
        }
        float* ob = out + (size_t)b * (NTOK * 256);
        #pragma unroll
        for (int ntl = 0; ntl < 2; ++ntl) {
            int n = (wid * 2 + ntl) * 16 + fr;
            float bpn = bp[n];
            #pragma unroll
            for (int mt = 0; mt < 4; ++mt)
                #pragma unroll
                for (int r = 0; r < 4; ++r) {
                    int tok = mt * 16 + 4 * g + r;
                    if (tok < NTOK) ob[tok * 256 + n] = acc[ntl][mt][r] + bpn;
                }
        }
    }
}

extern "C" void kernel_launch(void* const* d_in, const int* in_sizes, int n_in,
                              void* d_out, int out_size, void* d_ws, size_t ws_size,
                              hipStream_t stream) {
    const float* x          = (const float*)d_in[0];
    const float* bias_table = (const float*)d_in[1];
    const float* Wq         = (const float*)d_in[2];
    const float* bq         = (const float*)d_in[3];
    const float* Wk         = (const float*)d_in[4];
    const float* bk         = (const float*)d_in[5];
    const float* Wv         = (const float*)d_in[6];
    const float* bv         = (const float*)d_in[7];
    const float* Wp         = (const float*)d_in[8];
    const float* bp         = (const float*)d_in[9];
    const int*   rel_idx    = (const int*)d_in[10];
    float* out = (float*)d_out;

    // ws: wqkv f16 [768*256] | wp f16 [256*256] | biasm2 f32 [8*49*16*4]  (~610 KB)
    _Float16* wqkv  = (_Float16*)d_ws;
    _Float16* wp    = wqkv + 768 * 256;
    float*    biasm2 = (float*)(wp + 256 * 256);

    const int TOT = 768 * 256 + 256 * 256 + 8 * NTOK * 16;
    wa_prep<<<(TOT + 255) / 256, 256, 0, stream>>>(Wq, Wk, Wv, Wp, bias_table, rel_idx,
                                                   wqkv, wp, biasm2);
    wa_fused<<<4096, 512, 0, stream>>>(x, bq, bk, bv, bp, wqkv, wp, biasm2, out);
}

// Round 5
// 382.385 us; speedup vs baseline: 1.9174x; 1.1628x over previous
//
#include <hip/hip_runtime.h>

// WindowAttention fused kernel v5 for MI355X (gfx950).
// B=4096 windows, N=49, C=256, H=8, hd=32. fp32 in/out, f16 MFMA inside.
//
// One block = one window (512 thr = 8 waves), wave w owns head w end-to-end.
// LDS: xs (25.9 KB, x/ao staging) + per-wave 6272-B arena (q|k, aliased by P)
// = 76 KB -> 2 blocks/CU. v transposed in-register via ds_bpermute (no LDS).
// v5: v projection MOVED to after softmax (just before PV) so vT4's 16 regs
// are live across one phase boundary instead of four -- this was the last
// source of scratch spill under the 128-reg cap of launch_bounds(512,4)
// (r4 still spilled ~330 MB; r2/r3 ~1.6 GB).

#define NTOK 49
#define XPAD 264
#define SCALE_F 0.17677669529663687f

typedef _Float16 v8h __attribute__((ext_vector_type(8)));
typedef _Float16 v4h __attribute__((ext_vector_type(4)));
typedef float    v4f __attribute__((ext_vector_type(4)));
typedef int      v4i __attribute__((ext_vector_type(4)));

__device__ __forceinline__ v8h ldsv8(const _Float16* p) { return *(const v8h*)p; }
__device__ __forceinline__ int packh2(float lo, float hi) {
    unsigned short a = __builtin_bit_cast(unsigned short, (_Float16)lo);
    unsigned short b = __builtin_bit_cast(unsigned short, (_Float16)hi);
    return (int)((unsigned)a | ((unsigned)b << 16));
}

// ---------------- prep: f16 weights + float4-packed bias rows ----------------
__global__ void wa_prep(const float* __restrict__ Wq, const float* __restrict__ Wk,
                        const float* __restrict__ Wv, const float* __restrict__ Wp,
                        const float* __restrict__ bias_table, const int* __restrict__ rel_idx,
                        _Float16* __restrict__ wqkv, _Float16* __restrict__ wp,
                        float* __restrict__ biasm2) {
    int t = blockIdx.x * blockDim.x + threadIdx.x;
    const int NW = 768 * 256;
    const int NP = 256 * 256;
    const int NB4 = 8 * NTOK * 16;        // float4 units
    if (t < NW) {
        int n = t >> 8, k = t & 255;
        const float* W = (n < 256) ? Wq : (n < 512 ? Wk : Wv);
        wqkv[t] = (_Float16)W[(n & 255) * 256 + k];
    } else if (t < NW + NP) {
        int u = t - NW;
        wp[u] = (_Float16)Wp[u];
    } else if (t < NW + NP + NB4) {
        int u = t - NW - NP;               // (h*49 + row)*16 + fr
        int fr = u & 15;
        int hr = u >> 4;
        int row = hr % NTOK;
        int h = hr / NTOK;
        float4 v;
        float* vp = &v.x;
        #pragma unroll
        for (int c = 0; c < 4; ++c) {
            int col = fr + 16 * c;
            vp[c] = (col < NTOK) ? bias_table[rel_idx[row * NTOK + col] * 8 + h] : 0.f;
        }
        ((float4*)biasm2)[u] = v;
    }
}

// ---------------- fused window attention ----------------
__global__ __launch_bounds__(512, 4) void wa_fused(
    const float* __restrict__ x,
    const float* __restrict__ bq, const float* __restrict__ bk,
    const float* __restrict__ bv, const float* __restrict__ bp,
    const _Float16* __restrict__ wqkv, const _Float16* __restrict__ wp,
    const float* __restrict__ biasm2, float* __restrict__ out) {

    __shared__ _Float16 xs[NTOK * XPAD];     // 25,872 B  (x staging; ao after attn)
    __shared__ _Float16 arena[8 * 3136];     // 50,176 B  (per-wave: q[49][32]|k[49][32] -> P[49][64])

    const int b    = blockIdx.x;
    const int tid  = threadIdx.x;
    const int wid  = tid >> 6;
    const int lane = tid & 63;
    const int g    = lane >> 4;
    const int fr   = lane & 15;
    const int WB   = wid * 32;               // head-base column

    // ---- phase 1: stage x -> f16 LDS ----
    const float* xb = x + (size_t)b * (NTOK * 256);
    for (int i = tid; i < (NTOK * 256) / 4; i += 512) {
        float4 f = ((const float4*)xb)[i];
        int e = i * 4;
        v4h pk;
        pk[0] = (_Float16)f.x; pk[1] = (_Float16)f.y;
        pk[2] = (_Float16)f.z; pk[3] = (_Float16)f.w;
        *(v4h*)&xs[(e >> 8) * XPAD + (e & 255)] = pk;
    }
    __syncthreads();

    const v4f vzero = {0.f, 0.f, 0.f, 0.f};
    _Float16* wa = &arena[wid * 3136];

    // ---- phase 2q / 2k: two low-pressure passes (32 accums each) ----
    #pragma unroll
    for (int qk = 0; qk < 2; ++qk) {
        v4f acc[2][4];
        #pragma unroll
        for (int t = 0; t < 2; ++t)
            #pragma unroll
            for (int mt = 0; mt < 4; ++mt) acc[t][mt] = vzero;
        #pragma unroll
        for (int ks = 0; ks < 8; ++ks) {
            v8h a[4];
            #pragma unroll
            for (int mt = 0; mt < 4; ++mt) {
                int row = mt * 16 + fr; row = row > 48 ? 48 : row;
                a[mt] = ldsv8(&xs[row * XPAD + ks * 32 + g * 8]);
            }
            #pragma unroll
            for (int t = 0; t < 2; ++t) {
                int n = 256 * qk + WB + 16 * t + fr;
                v8h bf = *(const v8h*)&wqkv[n * 256 + ks * 32 + g * 8];
                #pragma unroll
                for (int mt = 0; mt < 4; ++mt)
                    acc[t][mt] = __builtin_amdgcn_mfma_f32_16x16x32_f16(a[mt], bf, acc[t][mt], 0, 0, 0);
            }
        }
        #pragma unroll
        for (int t = 0; t < 2; ++t) {
            float bias = qk ? bk[WB + 16 * t + fr] : bq[WB + 16 * t + fr];
            float scl  = qk ? 1.f : SCALE_F;
            int   base = qk ? 1568 : 0;
            int   d    = 16 * t + fr;
            #pragma unroll
            for (int mt = 0; mt < 4; ++mt)
                #pragma unroll
                for (int r = 0; r < 4; ++r) {
                    int tok = mt * 16 + 4 * g + r;
                    if (tok < NTOK) {
                        int ch = (d >> 3) ^ ((tok >> 2) & 3);
                        wa[base + tok * 32 + ch * 8 + (d & 7)] = (_Float16)((acc[t][mt][r] + bias) * scl);
                    }
                }
        }
        __builtin_amdgcn_sched_barrier(0);   // seal this pass's accumulators
    }
    // in-wave q/k write -> fragment read ordering (arena is wave-private)
    asm volatile("s_waitcnt lgkmcnt(0)" ::: "memory");
    __builtin_amdgcn_sched_barrier(0);

    // ---- phase 3: QK^T + softmax + P (pre-normalized), per-mt to cap regs ----
    {
        // preload ALL q/k fragments: P writes below alias the same arena bytes
        v8h ap4[4], bk4[4];
        #pragma unroll
        for (int t = 0; t < 4; ++t) {
            int row = t * 16 + fr; row = row > 48 ? 48 : row;
            int c = (row >> 2) & 3;
            ap4[t] = ldsv8(&wa[row * 32 + (g ^ c) * 8]);
            bk4[t] = ldsv8(&wa[1568 + row * 32 + (g ^ c) * 8]);
        }
        asm volatile("s_waitcnt lgkmcnt(0)" ::: "memory");   // frags in regs before overwrite
        __builtin_amdgcn_sched_barrier(0);

        #pragma unroll
        for (int mt = 0; mt < 4; ++mt) {
            v4f s[4];
            #pragma unroll
            for (int nt = 0; nt < 4; ++nt)
                s[nt] = __builtin_amdgcn_mfma_f32_16x16x32_f16(ap4[mt], bk4[nt], vzero, 0, 0, 0);
            #pragma unroll
            for (int r = 0; r < 4; ++r) {
                int row  = mt * 16 + 4 * g + r;
                int brow = row > 48 ? 48 : row;
                float4 b4 = ((const float4*)biasm2)[(wid * NTOK + brow) * 16 + fr];
                const float* bp4 = &b4.x;
                float m = -3.0e38f;
                #pragma unroll
                for (int nt = 0; nt < 4; ++nt) {
                    float val = s[nt][r] + bp4[nt];
                    if (nt == 3 && fr > 0) val = -1.0e30f;   // col = 48+fr >= 49
                    s[nt][r] = val;
                    m = fmaxf(m, val);
                }
                #pragma unroll
                for (int off = 1; off < 16; off <<= 1) m = fmaxf(m, __shfl_xor(m, off));
                float sum = 0.f;
                #pragma unroll
                for (int nt = 0; nt < 4; ++nt) {
                    float p = __expf(s[nt][r] - m);
                    s[nt][r] = p;
                    sum += p;
                }
                #pragma unroll
                for (int off = 1; off < 16; off <<= 1) sum += __shfl_xor(sum, off);
                float inv = __builtin_amdgcn_rcpf(sum);
                if (row < NTOK) {
                    #pragma unroll
                    for (int nt = 0; nt < 4; ++nt) {
                        int col = nt * 16 + fr;
                        wa[row * 64 + (col ^ ((row & 7) << 3))] = (_Float16)(s[nt][r] * inv);
                    }
                }
            }
        }
    }
    __builtin_amdgcn_sched_barrier(0);   // seal softmax live set

    // ---- phase 2v (moved): this head's v, D-layout in regs -> in-register transpose ----
    // Legal here: reads only xs (still intact; ao writes happen after the barrier
    // below) and leaves P untouched. vT4 now lives across ONE phase boundary.
    v4i vT4[2][2];   // [ntd][ks] = v8h B-frag for PV
    {
        v4f av[2][4];
        #pragma unroll
        for (int vl = 0; vl < 2; ++vl)
            #pragma unroll
            for (int mt = 0; mt < 4; ++mt) av[vl][mt] = vzero;
        #pragma unroll
        for (int ks = 0; ks < 8; ++ks) {
            v8h a[4];
            #pragma unroll
            for (int mt = 0; mt < 4; ++mt) {
                int row = mt * 16 + fr; row = row > 48 ? 48 : row;
                a[mt] = ldsv8(&xs[row * XPAD + ks * 32 + g * 8]);
            }
            #pragma unroll
            for (int vl = 0; vl < 2; ++vl) {
                v8h bf = *(const v8h*)&wqkv[(512 + WB + 16 * vl + fr) * 256 + ks * 32 + g * 8];
                #pragma unroll
                for (int mt = 0; mt < 4; ++mt)
                    av[vl][mt] = __builtin_amdgcn_mfma_f32_16x16x32_f16(a[mt], bf, av[vl][mt], 0, 0, 0);
            }
        }
        // bias + zero-pad toks>=49 + pack pairs (r=2p, 2p+1)
        float bvv[2];
        bvv[0] = bv[WB + fr]; bvv[1] = bv[WB + 16 + fr];
        int pkv[2][4][2];
        #pragma unroll
        for (int vl = 0; vl < 2; ++vl)
            #pragma unroll
            for (int mt = 0; mt < 4; ++mt)
                #pragma unroll
                for (int p = 0; p < 2; ++p) {
                    int tl = mt * 16 + 4 * g + 2 * p;
                    float lo = (tl     < NTOK) ? av[vl][mt][2 * p]     + bvv[vl] : 0.f;
                    float hi = (tl + 1 < NTOK) ? av[vl][mt][2 * p + 1] + bvv[vl] : 0.f;
                    pkv[vl][mt][p] = packh2(lo, hi);
                }
        // bpermute transpose: target word w' of B-frag[ntd][ks]:
        //   src lane = 16*((2g + (w'>>1))&3) + fr ; src word pkv[ntd][2ks+(g>>1)][w'&1]
        int addrA = 4 * (16 * ((2 * g) & 3) + fr);       // w' = 0,1
        int addrB = 4 * (16 * ((2 * g + 1) & 3) + fr);   // w' = 2,3
        #pragma unroll
        for (int ntd = 0; ntd < 2; ++ntd)
            #pragma unroll
            for (int ks = 0; ks < 2; ++ks)
                #pragma unroll
                for (int w = 0; w < 4; ++w) {
                    int ad = (w < 2) ? addrA : addrB;
                    int b0 = __builtin_amdgcn_ds_bpermute(ad, pkv[ntd][2 * ks][w & 1]);
                    int b1 = __builtin_amdgcn_ds_bpermute(ad, pkv[ntd][2 * ks + 1][w & 1]);
                    vT4[ntd][ks][w] = (g < 2) ? b0 : b1;
                }
    }
    __syncthreads();   // all waves done reading xs; P writes drained (barrier waitcnt)

    // ---- phase 3b: PV (v from registers) ----
    {
        v4f o[4][2];
        #pragma unroll
        for (int mt = 0; mt < 4; ++mt) { o[mt][0] = vzero; o[mt][1] = vzero; }
        #pragma unroll
        for (int mt = 0; mt < 4; ++mt) {
            int row = mt * 16 + fr; row = row > 48 ? 48 : row;
            int r7 = row & 7;
            #pragma unroll
            for (int ks = 0; ks < 2; ++ks) {
                v8h ap = ldsv8(&wa[row * 64 + ((4 * ks + g) ^ r7) * 8]);
                #pragma unroll
                for (int ntd = 0; ntd < 2; ++ntd) {
                    v8h bvv = __builtin_bit_cast(v8h, vT4[ntd][ks]);
                    o[mt][ntd] = __builtin_amdgcn_mfma_f32_16x16x32_f16(ap, bvv, o[mt][ntd], 0, 0, 0);
                }
            }
        }
        // ao -> xs (cols WB..WB+31), P was pre-normalized: no epilogue scaling
        #pragma unroll
        for (int mt = 0; mt < 4; ++mt)
            #pragma unroll
            for (int r = 0; r < 4; ++r) {
                int tok = mt * 16 + 4 * g + r;
                if (tok < NTOK) {
                    #pragma unroll
                    for (int ntd = 0; ntd < 2; ++ntd)
                        xs[tok * XPAD + WB + 16 * ntd + fr] = (_Float16)o[mt][ntd][r];
                }
            }
    }
    __syncthreads();   // all heads' ao staged

    // ---- phase 4: output projection ----
    {
        v4f acc[2][4];
        #pragma unroll
        for (int i = 0; i < 2; ++i)
            #pragma unroll
            for (int j = 0; j < 4; ++j) acc[i][j] = vzero;
        #pragma unroll
        for (int ks = 0; ks < 8; ++ks) {
            v8h a[4];
            #pragma unroll
            for (int mt = 0; mt < 4; ++mt) {
                int row = mt * 16 + fr; row = row > 48 ? 48 : row;
                a[mt] = ldsv8(&xs[row * XPAD + ks * 32 + g * 8]);
            }
            #pragma unroll
            for (int ntl = 0; ntl < 2; ++ntl) {
                int n = (wid * 2 + ntl) * 16 + fr;
                v8h bf = *(const v8h*)&wp[n * 256 + ks * 32 + g * 8];
                #pragma unroll
                for (int mt = 0; mt < 4; ++mt)
                    acc[ntl][mt] = __builtin_amdgcn_mfma_f32_16x16x32_f16(a[mt], bf, acc[ntl][mt], 0, 0, 0);
            }
        }
        float* ob = out + (size_t)b * (NTOK * 256);
        #pragma unroll
        for (int ntl = 0; ntl < 2; ++ntl) {
            int n = (wid * 2 + ntl) * 16 + fr;
            float bpn = bp[n];
            #pragma unroll
            for (int mt = 0; mt < 4; ++mt)
                #pragma unroll
                for (int r = 0; r < 4; ++r) {
                    int tok = mt * 16 + 4 * g + r;
                    if (tok < NTOK) ob[tok * 256 + n] = acc[ntl][mt][r] + bpn;
                }
        }
    }
}

extern "C" void kernel_launch(void* const* d_in, const int* in_sizes, int n_in,
                              void* d_out, int out_size, void* d_ws, size_t ws_size,
                              hipStream_t stream) {
    const float* x          = (const float*)d_in[0];
    const float* bias_table = (const float*)d_in[1];
    const float* Wq         = (const float*)d_in[2];
    const float* bq         = (const float*)d_in[3];
    const float* Wk         = (const float*)d_in[4];
    const float* bk         = (const float*)d_in[5];
    const float* Wv         = (const float*)d_in[6];
    const float* bv         = (const float*)d_in[7];
    const float* Wp         = (const float*)d_in[8];
    const float* bp         = (const float*)d_in[9];
    const int*   rel_idx    = (const int*)d_in[10];
    float* out = (float*)d_out;

    // ws: wqkv f16 [768*256] | wp f16 [256*256] | biasm2 f32 [8*49*16*4]  (~610 KB)
    _Float16* wqkv  = (_Float16*)d_ws;
    _Float16* wp    = wqkv + 768 * 256;
    float*    biasm2 = (float*)(wp + 256 * 256);

    const int TOT = 768 * 256 + 256 * 256 + 8 * NTOK * 16;
    wa_prep<<<(TOT + 255) / 256, 256, 0, stream>>>(Wq, Wk, Wv, Wp, bias_table, rel_idx,
                                                   wqkv, wp, biasm2);
    wa_fused<<<4096, 512, 0, stream>>>(x, bq, bk, bv, bp, wqkv, wp, biasm2, out);
}